// Round 1
// baseline (1302.870 us; speedup 1.0000x reference)
//
#include <hip/hip_runtime.h>
#include <math.h>

// Problem constants (from reference)
#define BB 8
#define SS 4096
#define DD 512
#define HH 512
#define MM (BB*SS)          // 32768 rows

// GEMM tiling
constexpr int BM = 64, BN = 64, BK = 16;

// Scan chunking
constexpr int TCH = 64;              // timesteps per chunk
constexpr int NC  = SS / TCH;        // 64 chunks
constexpr int BH  = BB * HH;         // 4096 channels

// ---------------------------------------------------------------------------
// Fused gate GEMM: for each (m,n) computes
//   kz = X[m,:]·Wz[n,:] + bz[n],  kh = X[m,:]·Wh[n,:] + bh[n]
//   a  = sigmoid(-kz)  (= 1 - z),  v = sigmoid(kz) * g(kh)
// g(x) = x + 0.5 (x>=0) else sigmoid(x).
// X tile in LDS is shared by both weight matrices (halves X traffic).
// ---------------------------------------------------------------------------
__global__ __launch_bounds__(256)
void gemm_gate(const float* __restrict__ X, const float* __restrict__ Wz,
               const float* __restrict__ bz, const float* __restrict__ Wh,
               const float* __restrict__ bh, float* __restrict__ A,
               float* __restrict__ V)
{
    __shared__ float Xs[BK][BM + 1];   // [k][m], +1 pad breaks store conflicts
    __shared__ float Zs[BK][BN + 1];   // [k][n]
    __shared__ float Hs[BK][BN + 1];

    const int t  = threadIdx.x;
    const int tx = t & 15, ty = t >> 4;
    const int m0 = blockIdx.x * BM;
    const int n0 = blockIdx.y * BN;

    // cooperative load mapping: thread t loads a float4 from row lr, cols lc..lc+3
    const int lr = t >> 2;            // 0..63
    const int lc = (t & 3) * 4;       // 0,4,8,12

    float accz[4][4] = {{0.f}}, acch[4][4] = {{0.f}};

    for (int k0 = 0; k0 < DD; k0 += BK) {
        const float4 xv = *(const float4*)(X  + (size_t)(m0 + lr) * DD + k0 + lc);
        const float4 zv = *(const float4*)(Wz + (size_t)(n0 + lr) * DD + k0 + lc);
        const float4 hv = *(const float4*)(Wh + (size_t)(n0 + lr) * DD + k0 + lc);
        Xs[lc+0][lr] = xv.x; Xs[lc+1][lr] = xv.y; Xs[lc+2][lr] = xv.z; Xs[lc+3][lr] = xv.w;
        Zs[lc+0][lr] = zv.x; Zs[lc+1][lr] = zv.y; Zs[lc+2][lr] = zv.z; Zs[lc+3][lr] = zv.w;
        Hs[lc+0][lr] = hv.x; Hs[lc+1][lr] = hv.y; Hs[lc+2][lr] = hv.z; Hs[lc+3][lr] = hv.w;
        __syncthreads();

        #pragma unroll
        for (int kk = 0; kk < BK; ++kk) {
            float xa[4], wz_r[4], wh_r[4];
            #pragma unroll
            for (int i = 0; i < 4; ++i) xa[i] = Xs[kk][ty*4 + i];
            #pragma unroll
            for (int j = 0; j < 4; ++j) { wz_r[j] = Zs[kk][tx*4 + j]; wh_r[j] = Hs[kk][tx*4 + j]; }
            #pragma unroll
            for (int i = 0; i < 4; ++i)
                #pragma unroll
                for (int j = 0; j < 4; ++j) {
                    accz[i][j] = fmaf(xa[i], wz_r[j], accz[i][j]);
                    acch[i][j] = fmaf(xa[i], wh_r[j], acch[i][j]);
                }
        }
        __syncthreads();
    }

    #pragma unroll
    for (int i = 0; i < 4; ++i) {
        const int m = m0 + ty*4 + i;
        #pragma unroll
        for (int j = 0; j < 4; ++j) {
            const int n  = n0 + tx*4 + j;
            const float kz = accz[i][j] + bz[n];
            const float kh = acch[i][j] + bh[n];
            const float a  = 1.0f / (1.0f + __expf(kz));    // sigmoid(-kz) = 1 - z
            const float z  = 1.0f / (1.0f + __expf(-kz));   // sigmoid(kz)
            const float ht = (kh >= 0.0f) ? (kh + 0.5f)
                                          : (1.0f / (1.0f + __expf(-kh)));
            const size_t idx = (size_t)m * HH + n;
            A[idx] = a;
            V[idx] = z * ht;
        }
    }
}

// ---------------------------------------------------------------------------
// Scan pass A: per (b, h, chunk): local recurrence with h_init = 0 giving the
// chunk transfer (prodA, localV) such that h_end = prodA * h_start + localV.
// Loads are coalesced across h (thread = consecutive h).
// ---------------------------------------------------------------------------
__global__ __launch_bounds__(256)
void scan_chunks(const float* __restrict__ A, const float* __restrict__ V,
                 float* __restrict__ cA, float* __restrict__ cV)
{
    const int h = blockIdx.x * 256 + threadIdx.x;  // 0..HH-1
    const int b = blockIdx.y;
    const int c = blockIdx.z;
    float prod = 1.0f, hl = 0.0f;
    size_t base = ((size_t)(b * SS + c * TCH)) * HH + h;
    for (int tt = 0; tt < TCH; ++tt) {
        const float a = A[base], v = V[base];
        hl   = fmaf(a, hl, v);
        prod *= a;
        base += HH;
    }
    const size_t ci = (size_t)c * BH + b * HH + h;
    cA[ci] = prod;
    cV[ci] = hl;
}

// ---------------------------------------------------------------------------
// Scan pass B: per channel, sequential over the 64 chunks: computes h_start of
// every chunk. Also writes the layer's final hidden state (= finals output).
// ---------------------------------------------------------------------------
__global__ __launch_bounds__(256)
void scan_carry(const float* __restrict__ cA, const float* __restrict__ cV,
                float* __restrict__ hstart, float* __restrict__ finals)
{
    const int ch = blockIdx.x * 256 + threadIdx.x;  // 0..BH-1
    float carry = 0.5f;                              // h0 = g(0) = 0.5
    for (int c = 0; c < NC; ++c) {
        const size_t ci = (size_t)c * BH + ch;
        hstart[ci] = carry;
        carry = fmaf(cA[ci], carry, cV[ci]);
    }
    finals[ch] = carry;
}

// ---------------------------------------------------------------------------
// Scan pass C: re-run each chunk with the correct carry-in, write h.
// ---------------------------------------------------------------------------
__global__ __launch_bounds__(256)
void scan_apply(const float* __restrict__ A, const float* __restrict__ V,
                const float* __restrict__ hstart, float* __restrict__ out)
{
    const int h = blockIdx.x * 256 + threadIdx.x;
    const int b = blockIdx.y;
    const int c = blockIdx.z;
    float hcur = hstart[(size_t)c * BH + b * HH + h];
    size_t base = ((size_t)(b * SS + c * TCH)) * HH + h;
    for (int tt = 0; tt < TCH; ++tt) {
        hcur = fmaf(A[base], hcur, V[base]);
        out[base] = hcur;
        base += HH;
    }
}

// ---------------------------------------------------------------------------
// Orchestration. Layer-1 hidden sequence is written into d_out's main region;
// layer-2's GEMM fully consumes it before layer-2's pass C overwrites it
// (stream-ordered, so no hazard). ws usage: 2*M*H + 3*NC*BH floats ~= 131 MB.
// ---------------------------------------------------------------------------
extern "C" void kernel_launch(void* const* d_in, const int* in_sizes, int n_in,
                              void* d_out, int out_size, void* d_ws, size_t ws_size,
                              hipStream_t stream)
{
    const float* x   = (const float*)d_in[0];
    const float* wz0 = (const float*)d_in[1];
    const float* bz0 = (const float*)d_in[2];
    const float* wh0 = (const float*)d_in[3];
    const float* bh0 = (const float*)d_in[4];
    const float* wz1 = (const float*)d_in[5];
    const float* bz1 = (const float*)d_in[6];
    const float* wh1 = (const float*)d_in[7];
    const float* bh1 = (const float*)d_in[8];

    float* out    = (float*)d_out;               // (B,S,H) = layer-2 hidden seq
    float* finals = out + (size_t)MM * HH;       // (L,B,1,H) stacked finals

    float* Abuf   = (float*)d_ws;                       // M*H
    float* Vbuf   = Abuf + (size_t)MM * HH;             // M*H
    float* cA     = Vbuf + (size_t)MM * HH;             // NC*BH
    float* cV     = cA   + (size_t)NC * BH;             // NC*BH
    float* hstart = cV   + (size_t)NC * BH;             // NC*BH

    const dim3 gg(MM / BM, HH / BN);      // 512 x 8 blocks
    const dim3 gs(HH / 256, BB, NC);      // 2 x 8 x 64 blocks

    // ---- layer 0: input x, output -> d_out main region ----
    gemm_gate <<<gg, 256, 0, stream>>>(x, wz0, bz0, wh0, bh0, Abuf, Vbuf);
    scan_chunks<<<gs, 256, 0, stream>>>(Abuf, Vbuf, cA, cV);
    scan_carry <<<BH / 256, 256, 0, stream>>>(cA, cV, hstart, finals);       // finals[0]
    scan_apply <<<gs, 256, 0, stream>>>(Abuf, Vbuf, hstart, out);

    // ---- layer 1: input = layer-0 output (in d_out), output -> d_out ----
    gemm_gate <<<gg, 256, 0, stream>>>(out, wz1, bz1, wh1, bh1, Abuf, Vbuf);
    scan_chunks<<<gs, 256, 0, stream>>>(Abuf, Vbuf, cA, cV);
    scan_carry <<<BH / 256, 256, 0, stream>>>(cA, cV, hstart, finals + BH);  // finals[1]
    scan_apply <<<gs, 256, 0, stream>>>(Abuf, Vbuf, hstart, out);
}

// Round 2
// 403.232 us; speedup vs baseline: 3.2311x; 3.2311x over previous
//
#include <hip/hip_runtime.h>
#include <math.h>

// Problem constants (from reference)
#define BB 8
#define SS 4096
#define DD 512
#define HH 512
#define MM (BB*SS)          // 32768 rows

// Scan chunking
constexpr int TCH = 64;              // timesteps per chunk
constexpr int NC  = SS / TCH;        // 64 chunks
constexpr int BH  = BB * HH;         // 4096 channels

// MFMA GEMM tiling
constexpr int BM = 128;              // rows per block
constexpr int BN = 64;               // cols per block (per weight matrix)
constexpr int BK = 64;               // k per stage

typedef short  short8  __attribute__((ext_vector_type(8)));
typedef float  float4v __attribute__((ext_vector_type(4)));

__device__ inline unsigned short f2bf(float f) {
    union { float f; unsigned u; } v; v.f = f;
    unsigned r = v.u + 0x7FFF + ((v.u >> 16) & 1);   // RNE
    return (unsigned short)(r >> 16);
}

__device__ inline void async_copy16(const void* g, void* l) {
    __builtin_amdgcn_global_load_lds(
        (const __attribute__((address_space(1))) void*)g,
        (__attribute__((address_space(3))) void*)l, 16, 0, 0);
}

// ---------------------------------------------------------------------------
// fp32 -> bf16 conversion, 8 elems/thread
// ---------------------------------------------------------------------------
__global__ __launch_bounds__(256)
void conv_bf16(const float* __restrict__ in, short* __restrict__ out) {
    const size_t base = ((size_t)blockIdx.x * 256 + threadIdx.x) * 8;
    float4 a = *(const float4*)(in + base);
    float4 b = *(const float4*)(in + base + 4);
    short8 r;
    r[0] = f2bf(a.x); r[1] = f2bf(a.y); r[2] = f2bf(a.z); r[3] = f2bf(a.w);
    r[4] = f2bf(b.x); r[5] = f2bf(b.y); r[6] = f2bf(b.z); r[7] = f2bf(b.w);
    *(short8*)(out + base) = r;
}

// 4 weight matrices in one launch (blockIdx.y selects)
__global__ __launch_bounds__(256)
void conv_bf16_w4(const float* __restrict__ w0, const float* __restrict__ w1,
                  const float* __restrict__ w2, const float* __restrict__ w3,
                  short* __restrict__ out) {
    const float* src = (blockIdx.y == 0) ? w0 : (blockIdx.y == 1) ? w1
                     : (blockIdx.y == 2) ? w2 : w3;
    const size_t base = ((size_t)blockIdx.x * 256 + threadIdx.x) * 8;
    float4 a = *(const float4*)(src + base);
    float4 b = *(const float4*)(src + base + 4);
    short8 r;
    r[0] = f2bf(a.x); r[1] = f2bf(a.y); r[2] = f2bf(a.z); r[3] = f2bf(a.w);
    r[4] = f2bf(b.x); r[5] = f2bf(b.y); r[6] = f2bf(b.z); r[7] = f2bf(b.w);
    *(short8*)(out + (size_t)blockIdx.y * HH * DD + base) = r;
}

// ---------------------------------------------------------------------------
// MFMA gate GEMM (bf16 inputs, fp32 accumulate):
//   kz = X[m,:]·Wz[n,:]+bz[n], kh = X[m,:]·Wh[n,:]+bh[n]
//   A[m,n] = sigmoid(-kz); V[m,n] = sigmoid(kz)*g(kh)
// X tile (128x64) in LDS shared by both weight tiles (64x64 each).
// Staging via global_load_lds width=16 (LDS dest = wave base + lane*16 -> LDS
// layout MUST be unpadded row-major [rows][64] bf16).
// ---------------------------------------------------------------------------
__global__ __launch_bounds__(256)
void gemm_gate_mfma(const short* __restrict__ Xg, const short* __restrict__ Wz,
                    const float* __restrict__ bz, const short* __restrict__ Wh,
                    const float* __restrict__ bh, float* __restrict__ A,
                    float* __restrict__ V)
{
    __shared__ short lds[BM * BK + 2 * BN * BK];   // X | Z | H, 32 KB
    constexpr int ZOFF = BM * BK;
    constexpr int HOFF = BM * BK + BN * BK;

    const int t    = threadIdx.x;
    const int wave = t >> 6;
    const int lane = t & 63;
    const int col16 = lane & 15;
    const int quad  = lane >> 4;
    const int wm = wave >> 1;          // 0/1: which 64-row half
    const int wn = wave & 1;           // 0/1: which 32-col half
    const int m0 = blockIdx.x * BM;
    const int n0 = blockIdx.y * BN;

    float4v accz[4][2], acch[4][2];
    #pragma unroll
    for (int i = 0; i < 4; ++i)
        #pragma unroll
        for (int j = 0; j < 2; ++j) {
            accz[i][j] = (float4v){0.f, 0.f, 0.f, 0.f};
            acch[i][j] = (float4v){0.f, 0.f, 0.f, 0.f};
        }

    const int lr = lane >> 3;          // 0..7 row within an 8-row wave-load
    const int lc = (lane & 7) * 8;     // 0..56 col (bf16 units)

    for (int k0 = 0; k0 < DD; k0 += BK) {
        // ---- stage X: 128 rows, wave handles rows [wave*32, wave*32+32) ----
        #pragma unroll
        for (int i = 0; i < 4; ++i) {
            const int r0 = wave * 32 + i * 8;
            async_copy16(Xg + (size_t)(m0 + r0 + lr) * DD + k0 + lc,
                         &lds[r0 * BK]);
        }
        // ---- stage Wz / Wh: 64 rows each, wave handles [wave*16, +16) ----
        #pragma unroll
        for (int i = 0; i < 2; ++i) {
            const int r0 = wave * 16 + i * 8;
            async_copy16(Wz + (size_t)(n0 + r0 + lr) * DD + k0 + lc,
                         &lds[ZOFF + r0 * BK]);
            async_copy16(Wh + (size_t)(n0 + r0 + lr) * DD + k0 + lc,
                         &lds[HOFF + r0 * BK]);
        }
        __syncthreads();   // drains vmcnt(0): staging complete

        #pragma unroll
        for (int kk = 0; kk < 2; ++kk) {
            short8 af[4], bzf[2], bhf[2];
            #pragma unroll
            for (int mi = 0; mi < 4; ++mi)
                af[mi] = *(const short8*)&lds[(wm*64 + mi*16 + col16) * BK + kk*32 + quad*8];
            #pragma unroll
            for (int nj = 0; nj < 2; ++nj) {
                bzf[nj] = *(const short8*)&lds[ZOFF + (wn*32 + nj*16 + col16) * BK + kk*32 + quad*8];
                bhf[nj] = *(const short8*)&lds[HOFF + (wn*32 + nj*16 + col16) * BK + kk*32 + quad*8];
            }
            #pragma unroll
            for (int mi = 0; mi < 4; ++mi)
                #pragma unroll
                for (int nj = 0; nj < 2; ++nj) {
                    accz[mi][nj] = __builtin_amdgcn_mfma_f32_16x16x32_bf16(af[mi], bzf[nj], accz[mi][nj], 0, 0, 0);
                    acch[mi][nj] = __builtin_amdgcn_mfma_f32_16x16x32_bf16(af[mi], bhf[nj], acch[mi][nj], 0, 0, 0);
                }
        }
        __syncthreads();   // LDS reused next iteration
    }

    // ---- epilogue: gates. C/D layout: col=lane&15, row=quad*4+reg ----
    #pragma unroll
    for (int nj = 0; nj < 2; ++nj) {
        const int n = n0 + wn*32 + nj*16 + col16;
        const float bzn = bz[n], bhn = bh[n];
        #pragma unroll
        for (int mi = 0; mi < 4; ++mi) {
            const int mbase = m0 + wm*64 + mi*16 + quad*4;
            #pragma unroll
            for (int reg = 0; reg < 4; ++reg) {
                const float kz = accz[mi][nj][reg] + bzn;
                const float kh = acch[mi][nj][reg] + bhn;
                const float a  = 1.0f / (1.0f + __expf(kz));    // 1 - z
                const float z  = 1.0f / (1.0f + __expf(-kz));   // z
                const float ht = (kh >= 0.0f) ? (kh + 0.5f)
                                              : (1.0f / (1.0f + __expf(-kh)));
                const size_t idx = (size_t)(mbase + reg) * HH + n;
                A[idx] = a;
                V[idx] = z * ht;
            }
        }
    }
}

// ---------------------------------------------------------------------------
// Scan pass A: per (b,h,chunk) local recurrence with h_init=0 -> (prodA, localV)
// ---------------------------------------------------------------------------
__global__ __launch_bounds__(256)
void scan_chunks(const float* __restrict__ A, const float* __restrict__ V,
                 float* __restrict__ cA, float* __restrict__ cV)
{
    const int h = blockIdx.x * 256 + threadIdx.x;
    const int b = blockIdx.y;
    const int c = blockIdx.z;
    float prod = 1.0f, hl = 0.0f;
    size_t base = ((size_t)(b * SS + c * TCH)) * HH + h;
    for (int tt = 0; tt < TCH; ++tt) {
        const float a = A[base], v = V[base];
        hl   = fmaf(a, hl, v);
        prod *= a;
        base += HH;
    }
    const size_t ci = (size_t)c * BH + b * HH + h;
    cA[ci] = prod;
    cV[ci] = hl;
}

// ---------------------------------------------------------------------------
// Scan pass B: sequential over chunks per channel; emits finals for free.
// ---------------------------------------------------------------------------
__global__ __launch_bounds__(256)
void scan_carry(const float* __restrict__ cA, const float* __restrict__ cV,
                float* __restrict__ hstart, float* __restrict__ finals)
{
    const int ch = blockIdx.x * 256 + threadIdx.x;
    float carry = 0.5f;                 // h0 = g(0) = 0.5
    for (int c = 0; c < NC; ++c) {
        const size_t ci = (size_t)c * BH + ch;
        hstart[ci] = carry;
        carry = fmaf(cA[ci], carry, cV[ci]);
    }
    finals[ch] = carry;
}

// ---------------------------------------------------------------------------
// Scan pass C (fp32 out): final layer -> d_out
// ---------------------------------------------------------------------------
__global__ __launch_bounds__(256)
void scan_apply_f32(const float* __restrict__ A, const float* __restrict__ V,
                    const float* __restrict__ hstart, float* __restrict__ out)
{
    const int h = blockIdx.x * 256 + threadIdx.x;
    const int b = blockIdx.y;
    const int c = blockIdx.z;
    float hcur = hstart[(size_t)c * BH + b * HH + h];
    size_t base = ((size_t)(b * SS + c * TCH)) * HH + h;
    for (int tt = 0; tt < TCH; ++tt) {
        hcur = fmaf(A[base], hcur, V[base]);
        out[base] = hcur;
        base += HH;
    }
}

// ---------------------------------------------------------------------------
// Scan pass C (bf16 out): layer-0 hidden seq feeds only layer-1's GEMM.
// ---------------------------------------------------------------------------
__global__ __launch_bounds__(256)
void scan_apply_bf16(const float* __restrict__ A, const float* __restrict__ V,
                     const float* __restrict__ hstart, short* __restrict__ out)
{
    const int h = blockIdx.x * 256 + threadIdx.x;
    const int b = blockIdx.y;
    const int c = blockIdx.z;
    float hcur = hstart[(size_t)c * BH + b * HH + h];
    size_t base = ((size_t)(b * SS + c * TCH)) * HH + h;
    for (int tt = 0; tt < TCH; ++tt) {
        hcur = fmaf(A[base], hcur, V[base]);
        out[base] = (short)f2bf(hcur);
        base += HH;
    }
}

// ---------------------------------------------------------------------------
// Orchestration.  ws: Abuf(64MB) Vbuf(64MB) Xbf(32MB) W4(2MB) cA/cV/hstart(3MB)
// ---------------------------------------------------------------------------
extern "C" void kernel_launch(void* const* d_in, const int* in_sizes, int n_in,
                              void* d_out, int out_size, void* d_ws, size_t ws_size,
                              hipStream_t stream)
{
    const float* x   = (const float*)d_in[0];
    const float* wz0 = (const float*)d_in[1];
    const float* bz0 = (const float*)d_in[2];
    const float* wh0 = (const float*)d_in[3];
    const float* bh0 = (const float*)d_in[4];
    const float* wz1 = (const float*)d_in[5];
    const float* bz1 = (const float*)d_in[6];
    const float* wh1 = (const float*)d_in[7];
    const float* bh1 = (const float*)d_in[8];

    float* out    = (float*)d_out;                // (B,S,H) layer-2 hidden seq
    float* finals = out + (size_t)MM * HH;        // (L,B,1,H)

    float* Abuf   = (float*)d_ws;                         // M*H f32
    float* Vbuf   = Abuf + (size_t)MM * HH;               // M*H f32
    short* Xbf    = (short*)(Vbuf + (size_t)MM * HH);     // M*D bf16
    short* Wbf    = Xbf + (size_t)MM * DD;                // 4 * H*D bf16
    float* cA     = (float*)(Wbf + (size_t)4 * HH * DD);  // NC*BH
    float* cV     = cA + (size_t)NC * BH;
    float* hstart = cV + (size_t)NC * BH;

    short* Wz0 = Wbf;
    short* Wh0 = Wbf + (size_t)1 * HH * DD;
    short* Wz1 = Wbf + (size_t)2 * HH * DD;
    short* Wh1 = Wbf + (size_t)3 * HH * DD;

    const dim3 gg(MM / BM, HH / BN);       // 256 x 8
    const dim3 gs(HH / 256, BB, NC);       // 2 x 8 x 64

    // ---- conversions ----
    conv_bf16   <<<MM * DD / 8 / 256, 256, 0, stream>>>(x, Xbf);
    conv_bf16_w4<<<dim3(HH * DD / 8 / 256, 4), 256, 0, stream>>>(wz0, wh0, wz1, wh1, Wbf);

    // ---- layer 0 ----
    gemm_gate_mfma<<<gg, 256, 0, stream>>>(Xbf, Wz0, bz0, Wh0, bh0, Abuf, Vbuf);
    scan_chunks   <<<gs, 256, 0, stream>>>(Abuf, Vbuf, cA, cV);
    scan_carry    <<<BH / 256, 256, 0, stream>>>(cA, cV, hstart, finals);        // finals[0]
    scan_apply_bf16<<<gs, 256, 0, stream>>>(Abuf, Vbuf, hstart, Xbf);            // bf16 h -> layer-1 input

    // ---- layer 1 ----
    gemm_gate_mfma<<<gg, 256, 0, stream>>>(Xbf, Wz1, bz1, Wh1, bh1, Abuf, Vbuf);
    scan_chunks   <<<gs, 256, 0, stream>>>(Abuf, Vbuf, cA, cV);
    scan_carry    <<<BH / 256, 256, 0, stream>>>(cA, cV, hstart, finals + BH);   // finals[1]
    scan_apply_f32<<<gs, 256, 0, stream>>>(Abuf, Vbuf, hstart, out);
}

// Round 3
// 339.778 us; speedup vs baseline: 3.8345x; 1.1868x over previous
//
#include <hip/hip_runtime.h>
#include <math.h>

// Problem constants (from reference)
#define BB 8
#define SS 4096
#define DD 512
#define HH 512
#define MM (BB*SS)          // 32768 rows

// Scan chunking
constexpr int TCH = 64;              // timesteps per chunk
constexpr int NC  = SS / TCH;        // 64 chunks
constexpr int BH  = BB * HH;         // 4096 channels

// MFMA GEMM tiling
constexpr int BM = 128;              // rows per block (= 2 chunks of 64 s)
constexpr int BN = 64;               // cols per block (per weight matrix)
constexpr int BK = 64;               // k per stage

typedef short  short8  __attribute__((ext_vector_type(8)));
typedef float  float4v __attribute__((ext_vector_type(4)));

__device__ inline unsigned short f2bf(float f) {
    union { float f; unsigned u; } v; v.f = f;
    unsigned r = v.u + 0x7FFF + ((v.u >> 16) & 1);   // RNE
    return (unsigned short)(r >> 16);
}
__device__ inline float bf_lo(unsigned u) {          // low 16 bits -> float
    union { unsigned u; float f; } x; x.u = u << 16; return x.f;
}
__device__ inline float bf_hi(unsigned u) {          // high 16 bits -> float
    union { unsigned u; float f; } x; x.u = u & 0xffff0000u; return x.f;
}

__device__ inline void async_copy16(const void* g, void* l) {
    __builtin_amdgcn_global_load_lds(
        (const __attribute__((address_space(1))) void*)g,
        (__attribute__((address_space(3))) void*)l, 16, 0, 0);
}

// ---------------------------------------------------------------------------
// fp32 -> bf16 conversion, 8 elems/thread
// ---------------------------------------------------------------------------
__global__ __launch_bounds__(256)
void conv_bf16(const float* __restrict__ in, short* __restrict__ out) {
    const size_t base = ((size_t)blockIdx.x * 256 + threadIdx.x) * 8;
    float4 a = *(const float4*)(in + base);
    float4 b = *(const float4*)(in + base + 4);
    short8 r;
    r[0] = f2bf(a.x); r[1] = f2bf(a.y); r[2] = f2bf(a.z); r[3] = f2bf(a.w);
    r[4] = f2bf(b.x); r[5] = f2bf(b.y); r[6] = f2bf(b.z); r[7] = f2bf(b.w);
    *(short8*)(out + base) = r;
}

// 4 weight matrices in one launch (blockIdx.y selects)
__global__ __launch_bounds__(256)
void conv_bf16_w4(const float* __restrict__ w0, const float* __restrict__ w1,
                  const float* __restrict__ w2, const float* __restrict__ w3,
                  short* __restrict__ out) {
    const float* src = (blockIdx.y == 0) ? w0 : (blockIdx.y == 1) ? w1
                     : (blockIdx.y == 2) ? w2 : w3;
    const size_t base = ((size_t)blockIdx.x * 256 + threadIdx.x) * 8;
    float4 a = *(const float4*)(src + base);
    float4 b = *(const float4*)(src + base + 4);
    short8 r;
    r[0] = f2bf(a.x); r[1] = f2bf(a.y); r[2] = f2bf(a.z); r[3] = f2bf(a.w);
    r[4] = f2bf(b.x); r[5] = f2bf(b.y); r[6] = f2bf(b.z); r[7] = f2bf(b.w);
    *(short8*)(out + (size_t)blockIdx.y * HH * DD + base) = r;
}

// ---------------------------------------------------------------------------
// MFMA gate GEMM + fused chunk-summary scan.
//   kz = X[m,:]·Wz[n,:]+bz[n], kh = X[m,:]·Wh[n,:]+bh[n]
//   a = sigmoid(-kz); v = (1-a)*g(kh); AV[m,n] = pack_bf16(v, a)
// Then each block (covering exactly 2 chunks of 64 timesteps for one b)
// computes chunk-local (prodA, localV) from the *rounded* a,v via LDS and
// writes cA/cV — eliminating the separate scan_chunks pass.
// LDS staging layout is unpadded row-major (global_load_lds requirement);
// the same 32 KB is reused for the packed a/v tile in the epilogue.
// ---------------------------------------------------------------------------
__global__ __launch_bounds__(256)
void gemm_gate_mfma(const short* __restrict__ Xg, const short* __restrict__ Wz,
                    const float* __restrict__ bz, const short* __restrict__ Wh,
                    const float* __restrict__ bh, unsigned* __restrict__ AV,
                    float* __restrict__ cA, float* __restrict__ cV)
{
    __shared__ char smem[32768];               // staging (32 KB) / av tile (32 KB)
    short*    lds    = (short*)smem;
    unsigned* lds_av = (unsigned*)smem;
    constexpr int ZOFF = BM * BK;
    constexpr int HOFF = BM * BK + BN * BK;

    const int t    = threadIdx.x;
    const int wave = t >> 6;
    const int lane = t & 63;
    const int col16 = lane & 15;
    const int quad  = lane >> 4;
    const int wm = wave >> 1;          // 0/1: which 64-row half
    const int wn = wave & 1;           // 0/1: which 32-col half
    const int m0 = blockIdx.x * BM;
    const int n0 = blockIdx.y * BN;

    float4v accz[4][2], acch[4][2];
    #pragma unroll
    for (int i = 0; i < 4; ++i)
        #pragma unroll
        for (int j = 0; j < 2; ++j) {
            accz[i][j] = (float4v){0.f, 0.f, 0.f, 0.f};
            acch[i][j] = (float4v){0.f, 0.f, 0.f, 0.f};
        }

    const int lr = lane >> 3;          // 0..7 row within an 8-row wave-load
    const int lc = (lane & 7) * 8;     // 0..56 col (bf16 units)

    for (int k0 = 0; k0 < DD; k0 += BK) {
        // ---- stage X: 128 rows, wave handles rows [wave*32, wave*32+32) ----
        #pragma unroll
        for (int i = 0; i < 4; ++i) {
            const int r0 = wave * 32 + i * 8;
            async_copy16(Xg + (size_t)(m0 + r0 + lr) * DD + k0 + lc,
                         &lds[r0 * BK]);
        }
        // ---- stage Wz / Wh: 64 rows each, wave handles [wave*16, +16) ----
        #pragma unroll
        for (int i = 0; i < 2; ++i) {
            const int r0 = wave * 16 + i * 8;
            async_copy16(Wz + (size_t)(n0 + r0 + lr) * DD + k0 + lc,
                         &lds[ZOFF + r0 * BK]);
            async_copy16(Wh + (size_t)(n0 + r0 + lr) * DD + k0 + lc,
                         &lds[HOFF + r0 * BK]);
        }
        __syncthreads();   // drains vmcnt(0): staging complete

        #pragma unroll
        for (int kk = 0; kk < 2; ++kk) {
            short8 af[4], bzf[2], bhf[2];
            #pragma unroll
            for (int mi = 0; mi < 4; ++mi)
                af[mi] = *(const short8*)&lds[(wm*64 + mi*16 + col16) * BK + kk*32 + quad*8];
            #pragma unroll
            for (int nj = 0; nj < 2; ++nj) {
                bzf[nj] = *(const short8*)&lds[ZOFF + (wn*32 + nj*16 + col16) * BK + kk*32 + quad*8];
                bhf[nj] = *(const short8*)&lds[HOFF + (wn*32 + nj*16 + col16) * BK + kk*32 + quad*8];
            }
            #pragma unroll
            for (int mi = 0; mi < 4; ++mi)
                #pragma unroll
                for (int nj = 0; nj < 2; ++nj) {
                    accz[mi][nj] = __builtin_amdgcn_mfma_f32_16x16x32_bf16(af[mi], bzf[nj], accz[mi][nj], 0, 0, 0);
                    acch[mi][nj] = __builtin_amdgcn_mfma_f32_16x16x32_bf16(af[mi], bhf[nj], acch[mi][nj], 0, 0, 0);
                }
        }
        __syncthreads();   // LDS reused next iteration (and by epilogue)
    }

    // ---- epilogue: gates -> packed bf16 (v|a), to global + LDS ----
    // C/D layout: col=lane&15, row=quad*4+reg (m89/m91-verified)
    #pragma unroll
    for (int nj = 0; nj < 2; ++nj) {
        const int ln = wn*32 + nj*16 + col16;
        const int n  = n0 + ln;
        const float bzn = bz[n], bhn = bh[n];
        #pragma unroll
        for (int mi = 0; mi < 4; ++mi) {
            const int lmb = wm*64 + mi*16 + quad*4;
            #pragma unroll
            for (int reg = 0; reg < 4; ++reg) {
                const float kz = accz[mi][nj][reg] + bzn;
                const float kh = acch[mi][nj][reg] + bhn;
                const float a  = 1.0f / (1.0f + __expf(kz));    // sigmoid(-kz) = 1-z
                const float ht = (kh >= 0.0f) ? (kh + 0.5f)
                                              : (1.0f / (1.0f + __expf(-kh)));
                const float v  = (1.0f - a) * ht;               // z * h_tilde
                const unsigned pav = ((unsigned)f2bf(v) << 16) | f2bf(a);
                const int lm = lmb + reg;
                AV[(size_t)(m0 + lm) * HH + n] = pav;
                lds_av[lm * 64 + ln] = pav;
            }
        }
    }
    __syncthreads();

    // ---- fused chunk-summary scan: 2 chunks x 64 cols = 128 tasks ----
    if (t < 128) {
        const int c  = t >> 6;          // chunk within block
        const int ln = t & 63;          // column
        float prod = 1.0f, hl = 0.0f;
        #pragma unroll 8
        for (int s = 0; s < TCH; ++s) {
            const unsigned u = lds_av[(c * TCH + s) * 64 + ln];
            const float a = bf_lo(u), v = bf_hi(u);
            hl   = fmaf(a, hl, v);
            prod *= a;
        }
        const int b  = m0 >> 12;                       // m0 / 4096
        const int cg = ((m0 & 4095) >> 6) + c;         // global chunk idx
        const size_t ci = (size_t)cg * BH + b * HH + (n0 + ln);
        cA[ci] = prod;
        cV[ci] = hl;
    }
}

// ---------------------------------------------------------------------------
// Scan pass B: sequential over chunks per channel; emits finals for free.
// ---------------------------------------------------------------------------
__global__ __launch_bounds__(256)
void scan_carry(const float* __restrict__ cA, const float* __restrict__ cV,
                float* __restrict__ hstart, float* __restrict__ finals)
{
    const int ch = blockIdx.x * 256 + threadIdx.x;
    float carry = 0.5f;                 // h0 = g(0) = 0.5
    for (int c = 0; c < NC; ++c) {
        const size_t ci = (size_t)c * BH + ch;
        hstart[ci] = carry;
        carry = fmaf(cA[ci], carry, cV[ci]);
    }
    finals[ch] = carry;
}

// ---------------------------------------------------------------------------
// Scan pass C (fp32 out): final layer -> d_out
// ---------------------------------------------------------------------------
__global__ __launch_bounds__(256)
void scan_apply_f32(const unsigned* __restrict__ AV,
                    const float* __restrict__ hstart, float* __restrict__ out)
{
    const int h = blockIdx.x * 256 + threadIdx.x;
    const int b = blockIdx.y;
    const int c = blockIdx.z;
    float hcur = hstart[(size_t)c * BH + b * HH + h];
    size_t base = ((size_t)(b * SS + c * TCH)) * HH + h;
    for (int tt = 0; tt < TCH; ++tt) {
        const unsigned u = AV[base];
        hcur = fmaf(bf_lo(u), hcur, bf_hi(u));
        out[base] = hcur;
        base += HH;
    }
}

// ---------------------------------------------------------------------------
// Scan pass C (bf16 out): layer-0 hidden seq feeds only layer-1's GEMM.
// ---------------------------------------------------------------------------
__global__ __launch_bounds__(256)
void scan_apply_bf16(const unsigned* __restrict__ AV,
                     const float* __restrict__ hstart, short* __restrict__ out)
{
    const int h = blockIdx.x * 256 + threadIdx.x;
    const int b = blockIdx.y;
    const int c = blockIdx.z;
    float hcur = hstart[(size_t)c * BH + b * HH + h];
    size_t base = ((size_t)(b * SS + c * TCH)) * HH + h;
    for (int tt = 0; tt < TCH; ++tt) {
        const unsigned u = AV[base];
        hcur = fmaf(bf_lo(u), hcur, bf_hi(u));
        out[base] = (short)f2bf(hcur);
        base += HH;
    }
}

// ---------------------------------------------------------------------------
// Orchestration.  ws: AV(67MB) Xbf(34MB) Wbf(2MB) cA/cV/hstart(3MB) ~ 106MB
// ---------------------------------------------------------------------------
extern "C" void kernel_launch(void* const* d_in, const int* in_sizes, int n_in,
                              void* d_out, int out_size, void* d_ws, size_t ws_size,
                              hipStream_t stream)
{
    const float* x   = (const float*)d_in[0];
    const float* wz0 = (const float*)d_in[1];
    const float* bz0 = (const float*)d_in[2];
    const float* wh0 = (const float*)d_in[3];
    const float* bh0 = (const float*)d_in[4];
    const float* wz1 = (const float*)d_in[5];
    const float* bz1 = (const float*)d_in[6];
    const float* wh1 = (const float*)d_in[7];
    const float* bh1 = (const float*)d_in[8];

    float* out    = (float*)d_out;                // (B,S,H) layer-2 hidden seq
    float* finals = out + (size_t)MM * HH;        // (L,B,1,H)

    unsigned* AV  = (unsigned*)d_ws;                      // M*H packed bf16 (v|a)
    short* Xbf    = (short*)(AV + (size_t)MM * HH);       // M*D bf16
    short* Wbf    = Xbf + (size_t)MM * DD;                // 4 * H*D bf16
    float* cA     = (float*)(Wbf + (size_t)4 * HH * DD);  // NC*BH
    float* cV     = cA + (size_t)NC * BH;
    float* hstart = cV + (size_t)NC * BH;

    short* Wz0 = Wbf;
    short* Wh0 = Wbf + (size_t)1 * HH * DD;
    short* Wz1 = Wbf + (size_t)2 * HH * DD;
    short* Wh1 = Wbf + (size_t)3 * HH * DD;

    const dim3 gg(MM / BM, HH / BN);       // 256 x 8
    const dim3 gs(HH / 256, BB, NC);       // 2 x 8 x 64

    // ---- conversions ----
    conv_bf16   <<<MM * DD / 8 / 256, 256, 0, stream>>>(x, Xbf);
    conv_bf16_w4<<<dim3(HH * DD / 8 / 256, 4), 256, 0, stream>>>(wz0, wh0, wz1, wh1, Wbf);

    // ---- layer 0 ----
    gemm_gate_mfma <<<gg, 256, 0, stream>>>(Xbf, Wz0, bz0, Wh0, bh0, AV, cA, cV);
    scan_carry     <<<BH / 256, 256, 0, stream>>>(cA, cV, hstart, finals);        // finals[0]
    scan_apply_bf16<<<gs, 256, 0, stream>>>(AV, hstart, Xbf);                     // bf16 h -> layer-1 input

    // ---- layer 1 ----
    gemm_gate_mfma <<<gg, 256, 0, stream>>>(Xbf, Wz1, bz1, Wh1, bh1, AV, cA, cV);
    scan_carry     <<<BH / 256, 256, 0, stream>>>(cA, cV, hstart, finals + BH);   // finals[1]
    scan_apply_f32 <<<gs, 256, 0, stream>>>(AV, hstart, out);
}

// Round 4
// 332.421 us; speedup vs baseline: 3.9193x; 1.0221x over previous
//
#include <hip/hip_runtime.h>
#include <math.h>

// Problem constants (from reference)
#define BB 8
#define SS 4096
#define DD 512
#define HH 512
#define MM (BB*SS)          // 32768 rows

// Scan chunking
constexpr int TCH = 64;              // timesteps per chunk
constexpr int NC  = SS / TCH;        // 64 chunks
constexpr int BH  = BB * HH;         // 4096 channels

// MFMA GEMM tiling
constexpr int BM = 128;              // rows per block (= 2 chunks of 64 s)
constexpr int BN = 64;               // cols per block (per weight matrix)
constexpr int BK = 64;               // k per stage

typedef short  short8  __attribute__((ext_vector_type(8)));
typedef float  float4v __attribute__((ext_vector_type(4)));

__device__ inline unsigned short f2bf(float f) {
    union { float f; unsigned u; } v; v.f = f;
    unsigned r = v.u + 0x7FFF + ((v.u >> 16) & 1);   // RNE
    return (unsigned short)(r >> 16);
}
__device__ inline float bf_lo(unsigned u) {          // low 16 bits -> float
    union { unsigned u; float f; } x; x.u = u << 16; return x.f;
}
__device__ inline float bf_hi(unsigned u) {          // high 16 bits -> float
    union { unsigned u; float f; } x; x.u = u & 0xffff0000u; return x.f;
}

__device__ inline void async_copy16(const void* g, void* l) {
    __builtin_amdgcn_global_load_lds(
        (const __attribute__((address_space(1))) void*)g,
        (__attribute__((address_space(3))) void*)l, 16, 0, 0);
}

// ---------------------------------------------------------------------------
// fp32 -> bf16 conversion, 8 elems/thread
// ---------------------------------------------------------------------------
__global__ __launch_bounds__(256)
void conv_bf16(const float* __restrict__ in, short* __restrict__ out) {
    const size_t base = ((size_t)blockIdx.x * 256 + threadIdx.x) * 8;
    float4 a = *(const float4*)(in + base);
    float4 b = *(const float4*)(in + base + 4);
    short8 r;
    r[0] = f2bf(a.x); r[1] = f2bf(a.y); r[2] = f2bf(a.z); r[3] = f2bf(a.w);
    r[4] = f2bf(b.x); r[5] = f2bf(b.y); r[6] = f2bf(b.z); r[7] = f2bf(b.w);
    *(short8*)(out + base) = r;
}

// 4 weight matrices in one launch (blockIdx.y selects)
__global__ __launch_bounds__(256)
void conv_bf16_w4(const float* __restrict__ w0, const float* __restrict__ w1,
                  const float* __restrict__ w2, const float* __restrict__ w3,
                  short* __restrict__ out) {
    const float* src = (blockIdx.y == 0) ? w0 : (blockIdx.y == 1) ? w1
                     : (blockIdx.y == 2) ? w2 : w3;
    const size_t base = ((size_t)blockIdx.x * 256 + threadIdx.x) * 8;
    float4 a = *(const float4*)(src + base);
    float4 b = *(const float4*)(src + base + 4);
    short8 r;
    r[0] = f2bf(a.x); r[1] = f2bf(a.y); r[2] = f2bf(a.z); r[3] = f2bf(a.w);
    r[4] = f2bf(b.x); r[5] = f2bf(b.y); r[6] = f2bf(b.z); r[7] = f2bf(b.w);
    *(short8*)(out + (size_t)blockIdx.y * HH * DD + base) = r;
}

// ---------------------------------------------------------------------------
// MFMA gate GEMM + fused chunk-summary scan.
//   kz = X[m,:]·Wz[n,:]+bz[n], kh = X[m,:]·Wh[n,:]+bh[n]
//   a = sigmoid(-kz); v = (1-a)*g(kh); AV[m,n] = pack_bf16(v, a)
// Packed a/v goes to LDS first; global stores are then fully coalesced
// (dwordx4, 256B-contiguous per 16 lanes). Each block (2 chunks x 64 cols)
// also emits the chunk-transfer summaries (prodA, localV) -> packed float2.
// ---------------------------------------------------------------------------
__global__ __launch_bounds__(256)
void gemm_gate_mfma(const short* __restrict__ Xg, const short* __restrict__ Wz,
                    const float* __restrict__ bz, const short* __restrict__ Wh,
                    const float* __restrict__ bh, unsigned* __restrict__ AV,
                    float2* __restrict__ cAV)
{
    __shared__ char smem[32768];               // staging (32 KB) / av tile (32 KB)
    short*    lds    = (short*)smem;
    unsigned* lds_av = (unsigned*)smem;
    constexpr int ZOFF = BM * BK;
    constexpr int HOFF = BM * BK + BN * BK;

    const int t    = threadIdx.x;
    const int wave = t >> 6;
    const int lane = t & 63;
    const int col16 = lane & 15;
    const int quad  = lane >> 4;
    const int wm = wave >> 1;          // 0/1: which 64-row half
    const int wn = wave & 1;           // 0/1: which 32-col half
    const int m0 = blockIdx.x * BM;
    const int n0 = blockIdx.y * BN;

    float4v accz[4][2], acch[4][2];
    #pragma unroll
    for (int i = 0; i < 4; ++i)
        #pragma unroll
        for (int j = 0; j < 2; ++j) {
            accz[i][j] = (float4v){0.f, 0.f, 0.f, 0.f};
            acch[i][j] = (float4v){0.f, 0.f, 0.f, 0.f};
        }

    const int lr = lane >> 3;          // 0..7 row within an 8-row wave-load
    const int lc = (lane & 7) * 8;     // 0..56 col (bf16 units)

    for (int k0 = 0; k0 < DD; k0 += BK) {
        // ---- stage X: 128 rows, wave handles rows [wave*32, wave*32+32) ----
        #pragma unroll
        for (int i = 0; i < 4; ++i) {
            const int r0 = wave * 32 + i * 8;
            async_copy16(Xg + (size_t)(m0 + r0 + lr) * DD + k0 + lc,
                         &lds[r0 * BK]);
        }
        // ---- stage Wz / Wh: 64 rows each, wave handles [wave*16, +16) ----
        #pragma unroll
        for (int i = 0; i < 2; ++i) {
            const int r0 = wave * 16 + i * 8;
            async_copy16(Wz + (size_t)(n0 + r0 + lr) * DD + k0 + lc,
                         &lds[ZOFF + r0 * BK]);
            async_copy16(Wh + (size_t)(n0 + r0 + lr) * DD + k0 + lc,
                         &lds[HOFF + r0 * BK]);
        }
        __syncthreads();   // drains vmcnt(0): staging complete

        #pragma unroll
        for (int kk = 0; kk < 2; ++kk) {
            short8 af[4], bzf[2], bhf[2];
            #pragma unroll
            for (int mi = 0; mi < 4; ++mi)
                af[mi] = *(const short8*)&lds[(wm*64 + mi*16 + col16) * BK + kk*32 + quad*8];
            #pragma unroll
            for (int nj = 0; nj < 2; ++nj) {
                bzf[nj] = *(const short8*)&lds[ZOFF + (wn*32 + nj*16 + col16) * BK + kk*32 + quad*8];
                bhf[nj] = *(const short8*)&lds[HOFF + (wn*32 + nj*16 + col16) * BK + kk*32 + quad*8];
            }
            #pragma unroll
            for (int mi = 0; mi < 4; ++mi)
                #pragma unroll
                for (int nj = 0; nj < 2; ++nj) {
                    accz[mi][nj] = __builtin_amdgcn_mfma_f32_16x16x32_bf16(af[mi], bzf[nj], accz[mi][nj], 0, 0, 0);
                    acch[mi][nj] = __builtin_amdgcn_mfma_f32_16x16x32_bf16(af[mi], bhf[nj], acch[mi][nj], 0, 0, 0);
                }
        }
        __syncthreads();   // LDS reused next iteration (and by epilogue)
    }

    // ---- epilogue: gates -> packed bf16 (v|a) into LDS ----
    // C/D layout: col=lane&15, row=quad*4+reg (m89/m91-verified)
    #pragma unroll
    for (int nj = 0; nj < 2; ++nj) {
        const int ln = wn*32 + nj*16 + col16;
        const int n  = n0 + ln;
        const float bzn = bz[n], bhn = bh[n];
        #pragma unroll
        for (int mi = 0; mi < 4; ++mi) {
            const int lmb = wm*64 + mi*16 + quad*4;
            #pragma unroll
            for (int reg = 0; reg < 4; ++reg) {
                const float kz = accz[mi][nj][reg] + bzn;
                const float kh = acch[mi][nj][reg] + bhn;
                const float a  = 1.0f / (1.0f + __expf(kz));    // sigmoid(-kz) = 1-z
                const float ht = (kh >= 0.0f) ? (kh + 0.5f)
                                              : (1.0f / (1.0f + __expf(-kh)));
                const float v  = (1.0f - a) * ht;               // z * h_tilde
                lds_av[(lmb + reg) * 64 + ln] = ((unsigned)f2bf(v) << 16) | f2bf(a);
            }
        }
    }
    __syncthreads();

    // ---- coalesced AV store: 128x64 dwords from LDS, dwordx4/thread ----
    {
        const int row0 = t >> 4;            // 0..15
        const int col  = (t & 15) * 4;      // 0..60
        #pragma unroll
        for (int i = 0; i < 8; ++i) {
            const int row = row0 + i * 16;
            const uint4 u = *(const uint4*)&lds_av[row * 64 + col];
            *(uint4*)&AV[(size_t)(m0 + row) * HH + n0 + col] = u;
        }
    }

    // ---- fused chunk-summary scan: 2 chunks x 64 cols = 128 tasks ----
    if (t < 128) {
        const int c  = t >> 6;          // chunk within block
        const int ln = t & 63;          // column
        float prod = 1.0f, hl = 0.0f;
        #pragma unroll 8
        for (int s = 0; s < TCH; ++s) {
            const unsigned u = lds_av[(c * TCH + s) * 64 + ln];
            const float a = bf_lo(u), v = bf_hi(u);
            hl   = fmaf(a, hl, v);
            prod *= a;
        }
        const int b  = m0 >> 12;                       // m0 / 4096
        const int cg = ((m0 & 4095) >> 6) + c;         // global chunk idx
        cAV[(size_t)cg * BH + b * HH + (n0 + ln)] = make_float2(prod, hl);
    }
}

// ---------------------------------------------------------------------------
// Scan apply (fp32 out, final layer): each (b,c) block computes its own carry
// prefix from the chunk summaries (coalesced, c cheap fmas), then replays its
// chunk. Last-chunk blocks also emit finals (= h at t = S-1).
// ---------------------------------------------------------------------------
__global__ __launch_bounds__(256)
void scan_apply_f32(const unsigned* __restrict__ AV,
                    const float2* __restrict__ cAV,
                    float* __restrict__ out, float* __restrict__ finals)
{
    const int h = blockIdx.x * 256 + threadIdx.x;
    const int b = blockIdx.y;
    const int c = blockIdx.z;
    const int ch = b * HH + h;
    float hcur = 0.5f;                  // h0 = g(0) = 0.5
    for (int cp = 0; cp < c; ++cp) {
        const float2 s = cAV[(size_t)cp * BH + ch];
        hcur = fmaf(s.x, hcur, s.y);
    }
    size_t base = ((size_t)(b * SS + c * TCH)) * HH + h;
    for (int tt = 0; tt < TCH; ++tt) {
        const unsigned u = AV[base];
        hcur = fmaf(bf_lo(u), hcur, bf_hi(u));
        out[base] = hcur;
        base += HH;
    }
    if (c == NC - 1) finals[ch] = hcur;
}

// ---------------------------------------------------------------------------
// Scan apply (bf16 out): layer-0 hidden seq feeds only layer-1's GEMM.
// ---------------------------------------------------------------------------
__global__ __launch_bounds__(256)
void scan_apply_bf16(const unsigned* __restrict__ AV,
                     const float2* __restrict__ cAV,
                     short* __restrict__ out, float* __restrict__ finals)
{
    const int h = blockIdx.x * 256 + threadIdx.x;
    const int b = blockIdx.y;
    const int c = blockIdx.z;
    const int ch = b * HH + h;
    float hcur = 0.5f;
    for (int cp = 0; cp < c; ++cp) {
        const float2 s = cAV[(size_t)cp * BH + ch];
        hcur = fmaf(s.x, hcur, s.y);
    }
    size_t base = ((size_t)(b * SS + c * TCH)) * HH + h;
    for (int tt = 0; tt < TCH; ++tt) {
        const unsigned u = AV[base];
        hcur = fmaf(bf_lo(u), hcur, bf_hi(u));
        out[base] = (short)f2bf(hcur);
        base += HH;
    }
    if (c == NC - 1) finals[ch] = hcur;
}

// ---------------------------------------------------------------------------
// Orchestration.  ws: AV(64MB) Xbf(32MB) Wbf(2MB) cAV(2MB) ~ 100MB
// ---------------------------------------------------------------------------
extern "C" void kernel_launch(void* const* d_in, const int* in_sizes, int n_in,
                              void* d_out, int out_size, void* d_ws, size_t ws_size,
                              hipStream_t stream)
{
    const float* x   = (const float*)d_in[0];
    const float* wz0 = (const float*)d_in[1];
    const float* bz0 = (const float*)d_in[2];
    const float* wh0 = (const float*)d_in[3];
    const float* bh0 = (const float*)d_in[4];
    const float* wz1 = (const float*)d_in[5];
    const float* bz1 = (const float*)d_in[6];
    const float* wh1 = (const float*)d_in[7];
    const float* bh1 = (const float*)d_in[8];

    float* out    = (float*)d_out;                // (B,S,H) layer-2 hidden seq
    float* finals = out + (size_t)MM * HH;        // (L,B,1,H)

    unsigned* AV  = (unsigned*)d_ws;                      // M*H packed bf16 (v|a)
    short* Xbf    = (short*)(AV + (size_t)MM * HH);       // M*D bf16
    short* Wbf    = Xbf + (size_t)MM * DD;                // 4 * H*D bf16
    float2* cAV   = (float2*)(Wbf + (size_t)4 * HH * DD); // NC*BH float2

    short* Wz0 = Wbf;
    short* Wh0 = Wbf + (size_t)1 * HH * DD;
    short* Wz1 = Wbf + (size_t)2 * HH * DD;
    short* Wh1 = Wbf + (size_t)3 * HH * DD;

    const dim3 gg(MM / BM, HH / BN);       // 256 x 8
    const dim3 gs(HH / 256, BB, NC);       // 2 x 8 x 64

    // ---- conversions ----
    conv_bf16   <<<MM * DD / 8 / 256, 256, 0, stream>>>(x, Xbf);
    conv_bf16_w4<<<dim3(HH * DD / 8 / 256, 4), 256, 0, stream>>>(wz0, wh0, wz1, wh1, Wbf);

    // ---- layer 0 ----
    gemm_gate_mfma <<<gg, 256, 0, stream>>>(Xbf, Wz0, bz0, Wh0, bh0, AV, cAV);
    scan_apply_bf16<<<gs, 256, 0, stream>>>(AV, cAV, Xbf, finals);            // finals[0]

    // ---- layer 1 ----
    gemm_gate_mfma <<<gg, 256, 0, stream>>>(Xbf, Wz1, bz1, Wh1, bh1, AV, cAV);
    scan_apply_f32 <<<gs, 256, 0, stream>>>(AV, cAV, out, finals + BH);       // finals[1]
}

// Round 5
// 322.662 us; speedup vs baseline: 4.0379x; 1.0302x over previous
//
#include <hip/hip_runtime.h>
#include <math.h>

// Problem constants (from reference)
#define BB 8
#define SS 4096
#define DD 512
#define HH 512
#define MM (BB*SS)          // 32768 rows

// Scan chunking
constexpr int TCH = 64;              // timesteps per chunk
constexpr int NC  = SS / TCH;        // 64 chunks
constexpr int BH  = BB * HH;         // 4096 channels

// MFMA GEMM tiling
constexpr int BM = 128;              // rows per block (= 2 chunks of 64 s)
constexpr int BN = 64;               // cols per block (per weight matrix)
constexpr int BK = 64;               // k per stage

typedef short  short8  __attribute__((ext_vector_type(8)));
typedef float  float4v __attribute__((ext_vector_type(4)));

__device__ inline unsigned short f2bf(float f) {
    union { float f; unsigned u; } v; v.f = f;
    unsigned r = v.u + 0x7FFF + ((v.u >> 16) & 1);   // RNE
    return (unsigned short)(r >> 16);
}
__device__ inline float bf_lo(unsigned u) {          // low 16 bits -> float
    union { unsigned u; float f; } x; x.u = u << 16; return x.f;
}
__device__ inline float bf_hi(unsigned u) {          // high 16 bits -> float
    union { unsigned u; float f; } x; x.u = u & 0xffff0000u; return x.f;
}
__device__ inline float fast_rcp(float x) {          // v_rcp_f32, ~1ulp(22b)
    return __builtin_amdgcn_rcpf(x);
}

__device__ inline void async_copy16(const void* g, void* l) {
    __builtin_amdgcn_global_load_lds(
        (const __attribute__((address_space(1))) void*)g,
        (__attribute__((address_space(3))) void*)l, 16, 0, 0);
}

// ---------------------------------------------------------------------------
// fp32 -> bf16 conversion for X (8192 blocks) and the 4 weights (4x128 blocks)
// in a single launch.
// ---------------------------------------------------------------------------
__global__ __launch_bounds__(256)
void conv_all(const float* __restrict__ x,
              const float* __restrict__ w0, const float* __restrict__ w1,
              const float* __restrict__ w2, const float* __restrict__ w3,
              short* __restrict__ Xbf, short* __restrict__ Wbf)
{
    constexpr int XBLK = MM * DD / 8 / 256;   // 8192
    constexpr int WBLK = HH * DD / 8 / 256;   // 128
    const int bid = blockIdx.x;
    const float* src; short* dst; size_t base;
    if (bid < XBLK) {
        src = x; dst = Xbf;
        base = ((size_t)bid * 256 + threadIdx.x) * 8;
    } else {
        const int idx  = bid - XBLK;
        const int wsel = idx / WBLK;
        src = (wsel == 0) ? w0 : (wsel == 1) ? w1 : (wsel == 2) ? w2 : w3;
        dst = Wbf + (size_t)wsel * HH * DD;
        base = ((size_t)(idx % WBLK) * 256 + threadIdx.x) * 8;
    }
    float4 a = *(const float4*)(src + base);
    float4 b = *(const float4*)(src + base + 4);
    short8 r;
    r[0] = f2bf(a.x); r[1] = f2bf(a.y); r[2] = f2bf(a.z); r[3] = f2bf(a.w);
    r[4] = f2bf(b.x); r[5] = f2bf(b.y); r[6] = f2bf(b.z); r[7] = f2bf(b.w);
    *(short8*)(dst + base) = r;
}

// ---------------------------------------------------------------------------
// MFMA gate GEMM + fused chunk-summary scan.
//   kz = X[m,:]·Wz[n,:]+bz[n], kh = X[m,:]·Wh[n,:]+bh[n]
//   a = sigmoid(-kz); v = (1-a)*g(kh); AV[m,n] = pack_bf16(v, a)
// Gate math uses v_exp/v_rcp intrinsics (no fp32 division sequences).
// Packed a/v goes to LDS, then coalesced dwordx4 global stores. Each block
// (2 chunks x 64 cols) emits chunk summaries (prodA, localV) -> float2,
// computed by all 256 threads (half-chunks) + __shfl_xor pair combine.
// ---------------------------------------------------------------------------
__global__ __launch_bounds__(256)
void gemm_gate_mfma(const short* __restrict__ Xg, const short* __restrict__ Wz,
                    const float* __restrict__ bz, const short* __restrict__ Wh,
                    const float* __restrict__ bh, unsigned* __restrict__ AV,
                    float2* __restrict__ cAV)
{
    __shared__ char smem[32768];               // staging (32 KB) / av tile (32 KB)
    short*    lds    = (short*)smem;
    unsigned* lds_av = (unsigned*)smem;
    constexpr int ZOFF = BM * BK;
    constexpr int HOFF = BM * BK + BN * BK;

    const int t    = threadIdx.x;
    const int wave = t >> 6;
    const int lane = t & 63;
    const int col16 = lane & 15;
    const int quad  = lane >> 4;
    const int wm = wave >> 1;          // 0/1: which 64-row half
    const int wn = wave & 1;           // 0/1: which 32-col half
    const int m0 = blockIdx.x * BM;
    const int n0 = blockIdx.y * BN;

    float4v accz[4][2], acch[4][2];
    #pragma unroll
    for (int i = 0; i < 4; ++i)
        #pragma unroll
        for (int j = 0; j < 2; ++j) {
            accz[i][j] = (float4v){0.f, 0.f, 0.f, 0.f};
            acch[i][j] = (float4v){0.f, 0.f, 0.f, 0.f};
        }

    const int lr = lane >> 3;          // 0..7 row within an 8-row wave-load
    const int lc = (lane & 7) * 8;     // 0..56 col (bf16 units)

    for (int k0 = 0; k0 < DD; k0 += BK) {
        // ---- stage X: 128 rows, wave handles rows [wave*32, wave*32+32) ----
        #pragma unroll
        for (int i = 0; i < 4; ++i) {
            const int r0 = wave * 32 + i * 8;
            async_copy16(Xg + (size_t)(m0 + r0 + lr) * DD + k0 + lc,
                         &lds[r0 * BK]);
        }
        // ---- stage Wz / Wh: 64 rows each, wave handles [wave*16, +16) ----
        #pragma unroll
        for (int i = 0; i < 2; ++i) {
            const int r0 = wave * 16 + i * 8;
            async_copy16(Wz + (size_t)(n0 + r0 + lr) * DD + k0 + lc,
                         &lds[ZOFF + r0 * BK]);
            async_copy16(Wh + (size_t)(n0 + r0 + lr) * DD + k0 + lc,
                         &lds[HOFF + r0 * BK]);
        }
        __syncthreads();   // drains vmcnt(0): staging complete

        #pragma unroll
        for (int kk = 0; kk < 2; ++kk) {
            short8 af[4], bzf[2], bhf[2];
            #pragma unroll
            for (int mi = 0; mi < 4; ++mi)
                af[mi] = *(const short8*)&lds[(wm*64 + mi*16 + col16) * BK + kk*32 + quad*8];
            #pragma unroll
            for (int nj = 0; nj < 2; ++nj) {
                bzf[nj] = *(const short8*)&lds[ZOFF + (wn*32 + nj*16 + col16) * BK + kk*32 + quad*8];
                bhf[nj] = *(const short8*)&lds[HOFF + (wn*32 + nj*16 + col16) * BK + kk*32 + quad*8];
            }
            #pragma unroll
            for (int mi = 0; mi < 4; ++mi)
                #pragma unroll
                for (int nj = 0; nj < 2; ++nj) {
                    accz[mi][nj] = __builtin_amdgcn_mfma_f32_16x16x32_bf16(af[mi], bzf[nj], accz[mi][nj], 0, 0, 0);
                    acch[mi][nj] = __builtin_amdgcn_mfma_f32_16x16x32_bf16(af[mi], bhf[nj], acch[mi][nj], 0, 0, 0);
                }
        }
        __syncthreads();   // LDS reused next iteration (and by epilogue)
    }

    // ---- epilogue: gates -> packed bf16 (v|a) into LDS ----
    // C/D layout: col=lane&15, row=quad*4+reg (m89/m91-verified)
    // a = rcp(1+exp(kz)); ht = kh>=0 ? kh+0.5 : rcp(1+exp(-kh)); v=(1-a)*ht
    #pragma unroll
    for (int nj = 0; nj < 2; ++nj) {
        const int ln = wn*32 + nj*16 + col16;
        const int n  = n0 + ln;
        const float bzn = bz[n], bhn = bh[n];
        #pragma unroll
        for (int mi = 0; mi < 4; ++mi) {
            const int lmb = wm*64 + mi*16 + quad*4;
            #pragma unroll
            for (int reg = 0; reg < 4; ++reg) {
                const float kz = accz[mi][nj][reg] + bzn;
                const float kh = acch[mi][nj][reg] + bhn;
                const float a  = fast_rcp(1.0f + __expf(kz));       // sigmoid(-kz)
                const float sn = fast_rcp(1.0f + __expf(-kh));      // sigmoid(kh)
                const float ht = (kh >= 0.0f) ? (kh + 0.5f) : sn;
                const float v  = (1.0f - a) * ht;                   // z * h_tilde
                lds_av[(lmb + reg) * 64 + ln] = ((unsigned)f2bf(v) << 16) | f2bf(a);
            }
        }
    }
    __syncthreads();

    // ---- coalesced AV store: 128x64 dwords from LDS, dwordx4/thread ----
    {
        const int row0 = t >> 4;            // 0..15
        const int col  = (t & 15) * 4;      // 0..60
        #pragma unroll
        for (int i = 0; i < 8; ++i) {
            const int row = row0 + i * 16;
            const uint4 u = *(const uint4*)&lds_av[row * 64 + col];
            *(uint4*)&AV[(size_t)(m0 + row) * HH + n0 + col] = u;
        }
    }

    // ---- fused chunk-summary scan: 128 channels x 2 halves = 256 tasks ----
    {
        const int task = t >> 1;            // 0..127: (chunk, column)
        const int hf   = t & 1;             // half of the 64-step chunk
        const int c    = task >> 6;
        const int ln   = task & 63;
        float prod = 1.0f, hl = 0.0f;
        #pragma unroll 8
        for (int s = 0; s < TCH / 2; ++s) {
            const unsigned u = lds_av[(c * TCH + hf * 32 + s) * 64 + ln];
            const float a = bf_lo(u), v = bf_hi(u);
            hl   = fmaf(a, hl, v);
            prod *= a;
        }
        // pair (hf=0: A0,V0 | hf=1: A1,V1); compose: (A0*A1, A1*V0 + V1)
        const float pA = __shfl_xor(prod, 1);
        const float pV = __shfl_xor(hl, 1);
        if (hf == 0) {
            const int b  = m0 >> 12;                    // m0 / 4096
            const int cg = ((m0 & 4095) >> 6) + c;      // global chunk idx
            cAV[(size_t)cg * BH + b * HH + (n0 + ln)] =
                make_float2(prod * pA, fmaf(pA, hl, pV));
        }
    }
}

// ---------------------------------------------------------------------------
// Scan apply (fp32 out, final layer): each (b,c) block computes its own carry
// prefix from the chunk summaries (coalesced, c cheap fmas), then replays its
// chunk. Last-chunk blocks also emit finals (= h at t = S-1).
// ---------------------------------------------------------------------------
__global__ __launch_bounds__(256)
void scan_apply_f32(const unsigned* __restrict__ AV,
                    const float2* __restrict__ cAV,
                    float* __restrict__ out, float* __restrict__ finals)
{
    const int h = blockIdx.x * 256 + threadIdx.x;
    const int b = blockIdx.y;
    const int c = blockIdx.z;
    const int ch = b * HH + h;
    float hcur = 0.5f;                  // h0 = g(0) = 0.5
    for (int cp = 0; cp < c; ++cp) {
        const float2 s = cAV[(size_t)cp * BH + ch];
        hcur = fmaf(s.x, hcur, s.y);
    }
    size_t base = ((size_t)(b * SS + c * TCH)) * HH + h;
    #pragma unroll 8
    for (int tt = 0; tt < TCH; ++tt) {
        const unsigned u = AV[base];
        hcur = fmaf(bf_lo(u), hcur, bf_hi(u));
        out[base] = hcur;
        base += HH;
    }
    if (c == NC - 1) finals[ch] = hcur;
}

// ---------------------------------------------------------------------------
// Scan apply (bf16 out): layer-0 hidden seq feeds only layer-1's GEMM.
// ---------------------------------------------------------------------------
__global__ __launch_bounds__(256)
void scan_apply_bf16(const unsigned* __restrict__ AV,
                     const float2* __restrict__ cAV,
                     short* __restrict__ out, float* __restrict__ finals)
{
    const int h = blockIdx.x * 256 + threadIdx.x;
    const int b = blockIdx.y;
    const int c = blockIdx.z;
    const int ch = b * HH + h;
    float hcur = 0.5f;
    for (int cp = 0; cp < c; ++cp) {
        const float2 s = cAV[(size_t)cp * BH + ch];
        hcur = fmaf(s.x, hcur, s.y);
    }
    size_t base = ((size_t)(b * SS + c * TCH)) * HH + h;
    #pragma unroll 8
    for (int tt = 0; tt < TCH; ++tt) {
        const unsigned u = AV[base];
        hcur = fmaf(bf_lo(u), hcur, bf_hi(u));
        out[base] = (short)f2bf(hcur);
        base += HH;
    }
    if (c == NC - 1) finals[ch] = hcur;
}

// ---------------------------------------------------------------------------
// Orchestration.  ws: AV(64MB) Xbf(32MB) Wbf(2MB) cAV(2MB) ~ 100MB
// ---------------------------------------------------------------------------
extern "C" void kernel_launch(void* const* d_in, const int* in_sizes, int n_in,
                              void* d_out, int out_size, void* d_ws, size_t ws_size,
                              hipStream_t stream)
{
    const float* x   = (const float*)d_in[0];
    const float* wz0 = (const float*)d_in[1];
    const float* bz0 = (const float*)d_in[2];
    const float* wh0 = (const float*)d_in[3];
    const float* bh0 = (const float*)d_in[4];
    const float* wz1 = (const float*)d_in[5];
    const float* bz1 = (const float*)d_in[6];
    const float* wh1 = (const float*)d_in[7];
    const float* bh1 = (const float*)d_in[8];

    float* out    = (float*)d_out;                // (B,S,H) layer-2 hidden seq
    float* finals = out + (size_t)MM * HH;        // (L,B,1,H)

    unsigned* AV  = (unsigned*)d_ws;                      // M*H packed bf16 (v|a)
    short* Xbf    = (short*)(AV + (size_t)MM * HH);       // M*D bf16
    short* Wbf    = Xbf + (size_t)MM * DD;                // 4 * H*D bf16
    float2* cAV   = (float2*)(Wbf + (size_t)4 * HH * DD); // NC*BH float2

    short* Wz0 = Wbf;
    short* Wh0 = Wbf + (size_t)1 * HH * DD;
    short* Wz1 = Wbf + (size_t)2 * HH * DD;
    short* Wh1 = Wbf + (size_t)3 * HH * DD;

    const dim3 gg(MM / BM, HH / BN);       // 256 x 8
    const dim3 gs(HH / 256, BB, NC);       // 2 x 8 x 64

    // ---- conversions (one launch: X + all 4 weights) ----
    conv_all<<<MM * DD / 8 / 256 + 4 * (HH * DD / 8 / 256), 256, 0, stream>>>(
        x, wz0, wh0, wz1, wh1, Xbf, Wbf);

    // ---- layer 0 ----
    gemm_gate_mfma <<<gg, 256, 0, stream>>>(Xbf, Wz0, bz0, Wh0, bh0, AV, cAV);
    scan_apply_bf16<<<gs, 256, 0, stream>>>(AV, cAV, Xbf, finals);            // finals[0]

    // ---- layer 1 ----
    gemm_gate_mfma <<<gg, 256, 0, stream>>>(Xbf, Wz1, bz1, Wh1, bh1, AV, cAV);
    scan_apply_f32 <<<gs, 256, 0, stream>>>(AV, cAV, out, finals + BH);       // finals[1]
}